// Round 1
// baseline (1255.897 us; speedup 1.0000x reference)
//
#include <hip/hip_runtime.h>

// Problem constants (match reference setup_inputs)
#define NB   50000   // nodes
#define BB   64      // batch  (== wavefront size: lane = b)
#define DD   16      // neighbors per node
#define NDRVN 1000   // driver nodes

// ---------------------------------------------------------------------------
// Transpose x (B,N) -> z0 (N,B).  Writes coalesced; reads hit L1 (16 reuses
// of each 64B line across consecutive waves).
__global__ __launch_bounds__(256) void transpose_kernel(
    const float* __restrict__ x, float* __restrict__ xT)
{
    int tid = blockIdx.x * 256 + threadIdx.x;   // tid = n*64 + b
    int n = tid >> 6;
    int b = tid & 63;
    if (n < NB) xT[tid] = x[b * NB + n];
}

// ---------------------------------------------------------------------------
// One 5->5 conv1x3 + relu layer, fully unrolled.  Weights come from global
// memory with wave-uniform addresses -> scalar loads into SGPRs; each fmaf is
// v_fma_f32 vdst, sgpr, vgpr, vgpr (exactly one SGPR operand - legal).
template<int WOUT>
__device__ __forceinline__ void conv5(const float (&in)[5][14], float (&out)[5][14],
                                      const float* __restrict__ w,
                                      const float* __restrict__ bias)
{
#pragma unroll
    for (int c = 0; c < 5; ++c) {
        float wr[15];
#pragma unroll
        for (int t = 0; t < 15; ++t) wr[t] = w[c * 15 + t];
        float bc = bias[c];
#pragma unroll
        for (int x = 0; x < WOUT; ++x) {
            float acc = bc;
#pragma unroll
            for (int ci = 0; ci < 5; ++ci) {
                acc = fmaf(wr[ci * 3 + 0], in[ci][x + 0], acc);
                acc = fmaf(wr[ci * 3 + 1], in[ci][x + 1], acc);
                acc = fmaf(wr[ci * 3 + 2], in[ci][x + 2], acc);
            }
            out[c][x] = fmaxf(acc, 0.0f);
        }
    }
}

// ---------------------------------------------------------------------------
// One full pass: gather 16 neighbors, run the 7-layer CNN, pair-average.
// Wave = one node n (uniform), lane = batch index b.  z layout (N, B).
__global__ __launch_bounds__(256) void pass_kernel(
    const float* __restrict__ zin, float* __restrict__ zout,
    const int*  __restrict__ nidx,
    const float* __restrict__ w0, const float* __restrict__ b0,
    const float* __restrict__ w1, const float* __restrict__ b1,
    const float* __restrict__ w2, const float* __restrict__ b2,
    const float* __restrict__ w3, const float* __restrict__ b3,
    const float* __restrict__ w4, const float* __restrict__ b4,
    const float* __restrict__ w5, const float* __restrict__ b5,
    const float* __restrict__ w6, const float* __restrict__ b6)
{
    int tid  = blockIdx.x * 256 + threadIdx.x;
    int lane = tid & 63;
    // grid is exact (N*B == 12500*256) so every wave is full; force n uniform
    int n = __builtin_amdgcn_readfirstlane(tid >> 6);

    // Neighbor indices: wave-uniform addresses -> s_load into SGPRs.
    const int* ip = nidx + n * DD;

    // Gather: 16 fully-coalesced 256B loads (uniform base + lane*4).
    float g[16];
#pragma unroll
    for (int d = 0; d < 16; ++d) {
        int j = ip[d];
        g[d] = zin[(size_t)j * BB + lane];
    }

    float ha[5][14], hb[5][14];

    // Layer 0: 1 -> 5 channels, width 16 -> 14
#pragma unroll
    for (int c = 0; c < 5; ++c) {
        float wa = w0[c * 3 + 0], wb = w0[c * 3 + 1], wc = w0[c * 3 + 2];
        float bc = b0[c];
#pragma unroll
        for (int x = 0; x < 14; ++x) {
            float acc = bc;
            acc = fmaf(wa, g[x + 0], acc);
            acc = fmaf(wb, g[x + 1], acc);
            acc = fmaf(wc, g[x + 2], acc);
            ha[c][x] = fmaxf(acc, 0.0f);
        }
    }

    conv5<12>(ha, hb, w1, b1);   // 14 -> 12
    conv5<10>(hb, ha, w2, b2);   // 12 -> 10
    conv5<8> (ha, hb, w3, b3);   // 10 -> 8
    conv5<6> (hb, ha, w4, b4);   // 8  -> 6
    conv5<4> (ha, hb, w5, b5);   // 6  -> 4

    // Layer 6: 5 -> 1, width 4 -> 2
    float t0 = b6[0], t1 = b6[0];
#pragma unroll
    for (int ci = 0; ci < 5; ++ci) {
        float wa = w6[ci * 3 + 0], wb = w6[ci * 3 + 1], wc = w6[ci * 3 + 2];
        t0 = fmaf(wa, hb[ci][0], t0);
        t0 = fmaf(wb, hb[ci][1], t0);
        t0 = fmaf(wc, hb[ci][2], t0);
        t1 = fmaf(wa, hb[ci][1], t1);
        t1 = fmaf(wb, hb[ci][2], t1);
        t1 = fmaf(wc, hb[ci][3], t1);
    }
    t0 = fmaxf(t0, 0.0f);
    t1 = fmaxf(t1, 0.0f);

    zout[(size_t)n * BB + lane] = 0.5f * (t0 + t1);
}

// ---------------------------------------------------------------------------
// Final driver gather: out[b, i] = z[driver_idx[i], b]   (out is (B, NDRV))
__global__ __launch_bounds__(256) void gather_out_kernel(
    const float* __restrict__ z, const int* __restrict__ didx,
    float* __restrict__ out)
{
    int i = blockIdx.x * 256 + threadIdx.x;
    if (i >= BB * NDRVN) return;
    int b = i / NDRVN;
    int k = i - b * NDRVN;
    out[i] = z[(size_t)didx[k] * BB + b];
}

// ---------------------------------------------------------------------------
extern "C" void kernel_launch(void* const* d_in, const int* in_sizes, int n_in,
                              void* d_out, int out_size, void* d_ws, size_t ws_size,
                              hipStream_t stream)
{
    const float* x    = (const float*)d_in[0];
    const int*   nidx = (const int*)  d_in[1];
    const int*   didx = (const int*)  d_in[2];
    const float* w[7];
    const float* b[7];
    for (int i = 0; i < 7; ++i) {
        w[i] = (const float*)d_in[3 + 2 * i];
        b[i] = (const float*)d_in[4 + 2 * i];
    }

    // Workspace: two ping-pong z buffers in (N, B) layout, 12.8 MB each.
    float* z0 = (float*)d_ws;
    float* z1 = z0 + (size_t)NB * BB;

    const int blocks = (NB * BB) / 256;   // 12500, exact

    transpose_kernel<<<blocks, 256, 0, stream>>>(x, z0);

    pass_kernel<<<blocks, 256, 0, stream>>>(z0, z1, nidx,
        w[0], b[0], w[1], b[1], w[2], b[2], w[3], b[3],
        w[4], b[4], w[5], b[5], w[6], b[6]);
    pass_kernel<<<blocks, 256, 0, stream>>>(z1, z0, nidx,
        w[0], b[0], w[1], b[1], w[2], b[2], w[3], b[3],
        w[4], b[4], w[5], b[5], w[6], b[6]);
    pass_kernel<<<blocks, 256, 0, stream>>>(z0, z1, nidx,
        w[0], b[0], w[1], b[1], w[2], b[2], w[3], b[3],
        w[4], b[4], w[5], b[5], w[6], b[6]);
    pass_kernel<<<blocks, 256, 0, stream>>>(z1, z0, nidx,
        w[0], b[0], w[1], b[1], w[2], b[2], w[3], b[3],
        w[4], b[4], w[5], b[5], w[6], b[6]);

    gather_out_kernel<<<(BB * NDRVN + 255) / 256, 256, 0, stream>>>(z0, didx, (float*)d_out);
}

// Round 2
// 1248.431 us; speedup vs baseline: 1.0060x; 1.0060x over previous
//
#include <hip/hip_runtime.h>

// Problem constants (match reference setup_inputs)
#define NB    50000   // nodes
#define BB    64      // batch  (== wavefront size: lane = b)
#define DD    16      // neighbors per node
#define NDRVN 1000    // driver nodes

// ---------------------------------------------------------------------------
// Transpose x (B,N) -> z0 (N,B).
__global__ __launch_bounds__(256) void transpose_kernel(
    const float* __restrict__ x, float* __restrict__ xT)
{
    int tid = blockIdx.x * 256 + threadIdx.x;   // tid = n*64 + b
    int n = tid >> 6;
    int b = tid & 63;
    if (n < NB) xT[tid] = x[b * NB + n];
}

// ---------------------------------------------------------------------------
// One 5->5 conv1x3 + relu layer, fully unrolled.  Weight addresses are
// wave-uniform -> s_load into SGPRs; fmaf is v_fma_f32 (sgpr, vgpr, vgpr).
template<int WOUT>
__device__ __forceinline__ void conv5(const float (&in)[5][14], float (&out)[5][14],
                                      const float* __restrict__ w,
                                      const float* __restrict__ bias)
{
#pragma unroll
    for (int c = 0; c < 5; ++c) {
        float wr[15];
#pragma unroll
        for (int t = 0; t < 15; ++t) wr[t] = w[c * 15 + t];
        float bc = bias[c];
#pragma unroll
        for (int x = 0; x < WOUT; ++x) {
            float acc = bc;
#pragma unroll
            for (int ci = 0; ci < 5; ++ci) {
                acc = fmaf(wr[ci * 3 + 0], in[ci][x + 0], acc);
                acc = fmaf(wr[ci * 3 + 1], in[ci][x + 1], acc);
                acc = fmaf(wr[ci * 3 + 2], in[ci][x + 2], acc);
            }
            out[c][x] = fmaxf(acc, 0.0f);
        }
    }
}

// ---------------------------------------------------------------------------
// One full pass: gather 16 neighbors, run the 7-layer CNN, pair-average.
// Wave = one node n (uniform), lane = batch index b.  z layout (N, B).
// __launch_bounds__(256, 2): min 2 waves/EU -> VGPR budget 256, so the
// ~150-float live set (g[16] + two [5][14] ping-pong arrays) stays in
// registers instead of spilling (R1 showed VGPR=44 + 2.4x VALU overhead).
__global__ __launch_bounds__(256, 2) void pass_kernel(
    const float* __restrict__ zin, float* __restrict__ zout,
    const int*  __restrict__ nidx,
    const float* __restrict__ w0, const float* __restrict__ b0,
    const float* __restrict__ w1, const float* __restrict__ b1,
    const float* __restrict__ w2, const float* __restrict__ b2,
    const float* __restrict__ w3, const float* __restrict__ b3,
    const float* __restrict__ w4, const float* __restrict__ b4,
    const float* __restrict__ w5, const float* __restrict__ b5,
    const float* __restrict__ w6, const float* __restrict__ b6)
{
    int tid  = blockIdx.x * 256 + threadIdx.x;
    int lane = tid & 63;
    // grid is exact (N*B == 12500*256) so every wave is full; force n uniform
    int n = __builtin_amdgcn_readfirstlane(tid >> 6);

    // Neighbor indices: wave-uniform addresses -> s_load into SGPRs.
    const int* ip = nidx + n * DD;

    // Gather: 16 fully-coalesced 256B loads (uniform base + lane*4).
    float g[16];
#pragma unroll
    for (int d = 0; d < 16; ++d) {
        int j = ip[d];
        g[d] = zin[(size_t)j * BB + lane];
    }

    float ha[5][14], hb[5][14];

    // Layer 0: 1 -> 5 channels, width 16 -> 14
#pragma unroll
    for (int c = 0; c < 5; ++c) {
        float wa = w0[c * 3 + 0], wb = w0[c * 3 + 1], wc = w0[c * 3 + 2];
        float bc = b0[c];
#pragma unroll
        for (int x = 0; x < 14; ++x) {
            float acc = bc;
            acc = fmaf(wa, g[x + 0], acc);
            acc = fmaf(wb, g[x + 1], acc);
            acc = fmaf(wc, g[x + 2], acc);
            ha[c][x] = fmaxf(acc, 0.0f);
        }
    }

    conv5<12>(ha, hb, w1, b1);   // 14 -> 12
    conv5<10>(hb, ha, w2, b2);   // 12 -> 10
    conv5<8> (ha, hb, w3, b3);   // 10 -> 8
    conv5<6> (hb, ha, w4, b4);   // 8  -> 6
    conv5<4> (ha, hb, w5, b5);   // 6  -> 4

    // Layer 6: 5 -> 1, width 4 -> 2
    float t0 = b6[0], t1 = b6[0];
#pragma unroll
    for (int ci = 0; ci < 5; ++ci) {
        float wa = w6[ci * 3 + 0], wb = w6[ci * 3 + 1], wc = w6[ci * 3 + 2];
        t0 = fmaf(wa, hb[ci][0], t0);
        t0 = fmaf(wb, hb[ci][1], t0);
        t0 = fmaf(wc, hb[ci][2], t0);
        t1 = fmaf(wa, hb[ci][1], t1);
        t1 = fmaf(wb, hb[ci][2], t1);
        t1 = fmaf(wc, hb[ci][3], t1);
    }
    t0 = fmaxf(t0, 0.0f);
    t1 = fmaxf(t1, 0.0f);

    zout[(size_t)n * BB + lane] = 0.5f * (t0 + t1);
}

// ---------------------------------------------------------------------------
// Final driver gather: out[b, i] = z[driver_idx[i], b]   (out is (B, NDRV))
__global__ __launch_bounds__(256) void gather_out_kernel(
    const float* __restrict__ z, const int* __restrict__ didx,
    float* __restrict__ out)
{
    int i = blockIdx.x * 256 + threadIdx.x;
    if (i >= BB * NDRVN) return;
    int b = i / NDRVN;
    int k = i - b * NDRVN;
    out[i] = z[(size_t)didx[k] * BB + b];
}

// ---------------------------------------------------------------------------
extern "C" void kernel_launch(void* const* d_in, const int* in_sizes, int n_in,
                              void* d_out, int out_size, void* d_ws, size_t ws_size,
                              hipStream_t stream)
{
    const float* x    = (const float*)d_in[0];
    const int*   nidx = (const int*)  d_in[1];
    const int*   didx = (const int*)  d_in[2];
    const float* w[7];
    const float* b[7];
    for (int i = 0; i < 7; ++i) {
        w[i] = (const float*)d_in[3 + 2 * i];
        b[i] = (const float*)d_in[4 + 2 * i];
    }

    // Workspace: two ping-pong z buffers in (N, B) layout, 12.8 MB each.
    float* z0 = (float*)d_ws;
    float* z1 = z0 + (size_t)NB * BB;

    const int blocks = (NB * BB) / 256;   // 12500, exact

    transpose_kernel<<<blocks, 256, 0, stream>>>(x, z0);

    pass_kernel<<<blocks, 256, 0, stream>>>(z0, z1, nidx,
        w[0], b[0], w[1], b[1], w[2], b[2], w[3], b[3],
        w[4], b[4], w[5], b[5], w[6], b[6]);
    pass_kernel<<<blocks, 256, 0, stream>>>(z1, z0, nidx,
        w[0], b[0], w[1], b[1], w[2], b[2], w[3], b[3],
        w[4], b[4], w[5], b[5], w[6], b[6]);
    pass_kernel<<<blocks, 256, 0, stream>>>(z0, z1, nidx,
        w[0], b[0], w[1], b[1], w[2], b[2], w[3], b[3],
        w[4], b[4], w[5], b[5], w[6], b[6]);
    pass_kernel<<<blocks, 256, 0, stream>>>(z1, z0, nidx,
        w[0], b[0], w[1], b[1], w[2], b[2], w[3], b[3],
        w[4], b[4], w[5], b[5], w[6], b[6]);

    gather_out_kernel<<<(BB * NDRVN + 255) / 256, 256, 0, stream>>>(z0, didx, (float*)d_out);
}